// Round 11
// baseline (426.346 us; speedup 1.0000x reference)
//
#include <hip/hip_runtime.h>
#include <hip/hip_bf16.h>

typedef __hip_bfloat16 bf16;
typedef __attribute__((ext_vector_type(8))) __bf16 bf16x8;
typedef __attribute__((ext_vector_type(4))) float floatx4;
typedef __attribute__((ext_vector_type(2))) float floatx2;

#define CHUNK 1024          // scan chunk (4 elems/thread, 256 threads)
#define CNT_BLOCKS 1024     // grid-stride blocks for edge counting

__device__ __forceinline__ unsigned short f2b(float f) {
    bf16 h = __float2bfloat16(f);
    unsigned short s;
    __builtin_memcpy(&s, &h, 2);
    return s;
}
__device__ __forceinline__ float b2f(unsigned short u) {
    unsigned int x = ((unsigned int)u) << 16;
    float f;
    __builtin_memcpy(&f, &x, 4);
    return f;
}
__device__ __forceinline__ float load_dual(const void* p, long long i, bool isbf) {
    return isbf ? b2f(((const unsigned short*)p)[i]) : ((const float*)p)[i];
}
__device__ __forceinline__ bf16x8 ldsfrag(const unsigned short* p) {
    union { uint4 u; bf16x8 v; } t;
    t.u = *(const uint4*)p;
    return t.v;
}
// 8 bf16 A-fragment from a dual-dtype [rows][stride] matrix, row-major
__device__ __forceinline__ bf16x8 gfrag_dual(const void* A, int row, int stride, int k0, bool isbf) {
    if (isbf) {
        union { uint4 u; bf16x8 v; } t;
        t.u = *(const uint4*)((const unsigned short*)A + (size_t)row * stride + k0);
        return t.v;
    }
    const float* ap = (const float*)A + (size_t)row * stride + k0;
    float4 v0 = ((const float4*)ap)[0];
    float4 v1 = ((const float4*)ap)[1];
    union { unsigned short s[8]; bf16x8 v; } t;
    t.s[0] = f2b(v0.x); t.s[1] = f2b(v0.y); t.s[2] = f2b(v0.z); t.s[3] = f2b(v0.w);
    t.s[4] = f2b(v1.x); t.s[5] = f2b(v1.y); t.s[6] = f2b(v1.z); t.s[7] = f2b(v1.w);
    return t.v;
}

// ---------------------------------------------------------------------------
// Dtype detection.
// ---------------------------------------------------------------------------
__global__ __launch_bounds__(64) void detect_kernel(const unsigned int* __restrict__ words,
                                                    int* __restrict__ flag) {
    int cnt = 0;
    for (int i = threadIdx.x; i < 4096; i += 64) {
        unsigned int lo = words[i] & 0xFFFFu;
        unsigned int e = (lo >> 7) & 0xFFu;
        if (lo == 0u || (e >= 110u && e <= 135u)) cnt++;
    }
#pragma unroll
    for (int off = 32; off > 0; off >>= 1) cnt += __shfl_down(cnt, off, 64);
    if (threadIdx.x == 0) *flag = (cnt > 2458) ? 1 : 0;
}

// ---------------------------------------------------------------------------
// Direct CSR pass 1: per-node degree count (non-returning atomics over N=100K
// counters = 6250 cache lines; vs the bucket design's 64 lines). No LDS
// atomics, no barriers in the edge path (R2-R8: bucket variants all stuck at
// 60-83us with every pipe idle). Blocks [0,256): weight transposes.
// ---------------------------------------------------------------------------
__global__ __launch_bounds__(256) void count_kernel(const int* __restrict__ dst,
                                                    int* __restrict__ ncount, int E,
                                                    const void* __restrict__ Wp,
                                                    const void* __restrict__ W1,
                                                    const void* __restrict__ W2,
                                                    unsigned short* __restrict__ Wtp,
                                                    unsigned short* __restrict__ Wt1,
                                                    unsigned short* __restrict__ Wt2,
                                                    const int* __restrict__ flag) {
    const int t = threadIdx.x;
    if (blockIdx.x < 256) {
        const bool isbf = (*flag != 0);
        int idx = blockIdx.x * 256 + t;
        if (idx < 16384) {
            int n = idx >> 7, k = idx & 127;
            Wtp[idx] = f2b(load_dual(Wp, (long long)k * 128 + n, isbf));
        } else if (idx < 49152) {
            int j = idx - 16384;
            int n = j >> 8, k = j & 255;
            Wt1[j] = f2b(load_dual(W1, (long long)k * 128 + n, isbf));
        } else if (idx < 65536) {
            int j = idx - 49152;
            int n = j >> 7, k = j & 127;
            Wt2[j] = f2b(load_dual(W2, (long long)k * 128 + n, isbf));
        }
        return;
    }
    int idx = ((int)blockIdx.x - 256) * 256 + t;
    const int stride = CNT_BLOCKS * 256;
    for (int e = idx; e < E; e += stride)
        atomicAdd(&ncount[dst[e]], 1);
}

// ---------------------------------------------------------------------------
// Scan tier 1: per-1024-chunk local exclusive scan -> row_start(local), csum.
// ---------------------------------------------------------------------------
__global__ __launch_bounds__(256) void scanp_kernel(const int* __restrict__ ncount,
                                                    int* __restrict__ row_start,
                                                    int* __restrict__ csum, int N) {
    const int t = threadIdx.x;
    const int base = blockIdx.x * CHUNK;
    int v[4];
    int sum = 0;
#pragma unroll
    for (int j = 0; j < 4; ++j) {
        int i = base + t * 4 + j;
        v[j] = (i < N) ? ncount[i] : 0;
        sum += v[j];
    }
    int lane = t & 63, wave = t >> 6;
    int inc = sum;
#pragma unroll
    for (int off = 1; off < 64; off <<= 1) {
        int x = __shfl_up(inc, off, 64);
        if (lane >= off) inc += x;
    }
    __shared__ int wsum[4];
    if (lane == 63) wsum[wave] = inc;
    __syncthreads();
    int woff = 0;
    for (int w = 0; w < wave; ++w) woff += wsum[w];
    int run = inc - sum + woff;
#pragma unroll
    for (int j = 0; j < 4; ++j) {
        int i = base + t * 4 + j;
        if (i < N) row_start[i] = run;
        run += v[j];
    }
    if (t == 255) csum[blockIdx.x] = run;
}

// ---------------------------------------------------------------------------
// Scan tier 2: single-block exclusive scan of chunk sums (NC <= 1024).
// ---------------------------------------------------------------------------
__global__ __launch_bounds__(256) void scant_kernel(const int* __restrict__ csum,
                                                    int* __restrict__ cbase, int NC) {
    const int t = threadIdx.x;
    int v[4];
    int sum = 0;
#pragma unroll
    for (int j = 0; j < 4; ++j) {
        int i = t * 4 + j;
        v[j] = (i < NC) ? csum[i] : 0;
        sum += v[j];
    }
    int lane = t & 63, wave = t >> 6;
    int inc = sum;
#pragma unroll
    for (int off = 1; off < 64; off <<= 1) {
        int x = __shfl_up(inc, off, 64);
        if (lane >= off) inc += x;
    }
    __shared__ int wsum[4];
    if (lane == 63) wsum[wave] = inc;
    __syncthreads();
    int woff = 0;
    for (int w = 0; w < wave; ++w) woff += wsum[w];
    int run = inc - sum + woff;
#pragma unroll
    for (int j = 0; j < 4; ++j) {
        int i = t * 4 + j;
        if (i < NC) cbase[i] = run;
        run += v[j];
    }
}

// ---------------------------------------------------------------------------
// Scan tier 3: add chunk base back; init cursor = row_start.
// ---------------------------------------------------------------------------
__global__ __launch_bounds__(256) void addback_kernel(int* __restrict__ row_start,
                                                      int* __restrict__ cursor,
                                                      const int* __restrict__ cbase, int N) {
    const int cb = cbase[blockIdx.x];
    int i0 = blockIdx.x * CHUNK + threadIdx.x * 4;
#pragma unroll
    for (int j = 0; j < 4; ++j) {
        int k = i0 + j;
        if (k < N) {
            int r = row_start[k] + cb;
            row_start[k] = r;
            cursor[k] = r;
        }
    }
}

// ---------------------------------------------------------------------------
// Fused: projection GEMM (blocks [0,gblocks)) + edge append (rest).
// Append role: pos = atomicAdd(&cursor[dst],1); rec[pos] = {src, exp(logit)}.
// Returning atomics over 100K counters (~16 hits each, 6250 lines), 4 edges/
// thread full-ILP, no LDS/barriers. MFMA gemm overlaps the atomic latency.
// ---------------------------------------------------------------------------
__global__ __launch_bounds__(256) void gemm_append_kernel(const void* __restrict__ A,
                                                          const unsigned short* __restrict__ Wt,
                                                          const void* __restrict__ bias,
                                                          unsigned short* __restrict__ hv,
                                                          const int* __restrict__ flag, int N,
                                                          int gblocks,
                                                          const int* __restrict__ dst,
                                                          const int* __restrict__ src,
                                                          const void* __restrict__ logits,
                                                          int* __restrict__ cursor,
                                                          uint2* __restrict__ rec, int E) {
    __shared__ unsigned short Wl[128 * 136];
    const int t = threadIdx.x;
    if ((int)blockIdx.x < gblocks) {
        // ---- projection GEMM role ----
        const bool isbf = (*flag != 0);
        const int wid = t >> 6, lane = t & 63;
        const int m16 = lane & 15, quad = lane >> 4;
        const int row0 = blockIdx.x * 128;
        {
            int r = t >> 1, kh = (t & 1) * 64;
            const uint4* s = (const uint4*)(Wt + (size_t)r * 128 + kh);
            uint4* d = (uint4*)&Wl[r * 136 + kh];
#pragma unroll
            for (int q = 0; q < 8; ++q) d[q] = s[q];
        }
        __syncthreads();

        floatx4 acc[2][8];
#pragma unroll
        for (int i = 0; i < 2; ++i)
#pragma unroll
            for (int j = 0; j < 8; ++j) acc[i][j] = (floatx4){0.f, 0.f, 0.f, 0.f};

        int ra0 = row0 + wid * 32 + m16;      if (ra0 >= N) ra0 = N - 1;
        int ra1 = row0 + wid * 32 + 16 + m16; if (ra1 >= N) ra1 = N - 1;

#pragma unroll
        for (int c = 0; c < 4; ++c) {
            int k0 = c * 32 + quad * 8;
            bf16x8 a0 = gfrag_dual(A, ra0, 128, k0, isbf);
            bf16x8 a1 = gfrag_dual(A, ra1, 128, k0, isbf);
#pragma unroll
            for (int nt = 0; nt < 8; ++nt) {
                bf16x8 b = ldsfrag(&Wl[(nt * 16 + m16) * 136 + k0]);
                acc[0][nt] = __builtin_amdgcn_mfma_f32_16x16x32_bf16(a0, b, acc[0][nt], 0, 0, 0);
                acc[1][nt] = __builtin_amdgcn_mfma_f32_16x16x32_bf16(a1, b, acc[1][nt], 0, 0, 0);
            }
        }

#pragma unroll
        for (int mt = 0; mt < 2; ++mt) {
            int gr0 = row0 + wid * 32 + mt * 16 + quad * 4;
#pragma unroll
            for (int nt = 0; nt < 8; ++nt) {
                int col = nt * 16 + m16;
                float bb = load_dual(bias, col, isbf);
#pragma unroll
                for (int rg = 0; rg < 4; ++rg) {
                    int gr = gr0 + rg;
                    if (gr < N) hv[(size_t)gr * 128 + col] = f2b(acc[mt][nt][rg] + bb);
                }
            }
        }
    } else {
        // ---- edge append role ----
        const bool isbf = (*flag != 0);
        int e0 = (((int)blockIdx.x - gblocks) * 256 + t) * 4;
        int d[4];
        unsigned int s4[4];
        float w[4];
        int nv = 0;
#pragma unroll
        for (int j = 0; j < 4; ++j) {
            int e = e0 + j;
            if (e < E) {
                d[j] = dst[e];
                s4[j] = (unsigned int)src[e];
                w[j] = expf(load_dual(logits, e, isbf));
                nv = j + 1;
            }
        }
        int pos[4];
#pragma unroll
        for (int j = 0; j < 4; ++j)
            if (j < nv) pos[j] = atomicAdd(&cursor[d[j]], 1);
#pragma unroll
        for (int j = 0; j < 4; ++j)
            if (j < nv) rec[pos[j]] = make_uint2(s4[j], __float_as_uint(w[j]));
    }
}

// ---------------------------------------------------------------------------
// Aggregation: one wave/node, 2 features/lane, register accumulation.
// Wave-uniform record stream via readfirstlane, 16-deep gather pipeline,
// 32-bit offset gather addressing, packed float2 accumulate.
// ---------------------------------------------------------------------------
__global__ __launch_bounds__(256) void agg_csr_kernel(const int* __restrict__ row_start,
                                                      const int* __restrict__ ncount,
                                                      const unsigned long long* __restrict__ erec,
                                                      const unsigned int* __restrict__ hv32,
                                                      unsigned int* __restrict__ ctx32, int N) {
    int n = blockIdx.x * 4 + (threadIdx.x >> 6);
    int lane = threadIdx.x & 63;
    if (n >= N) return;
    int s0 = __builtin_amdgcn_readfirstlane(row_start[n]);
    int deg = __builtin_amdgcn_readfirstlane(ncount[n]);
    const unsigned long long* ep = erec + s0;
    const unsigned int lb = (unsigned int)lane << 2;
    floatx2 acc = {0.f, 0.f};
    float z = 0.f;
    int i = 0;
    for (; i + 16 <= deg; i += 16) {
        unsigned long long r[16];
        unsigned int h[16];
#pragma unroll
        for (int j = 0; j < 16; ++j) r[j] = ep[i + j];
#pragma unroll
        for (int j = 0; j < 16; ++j) {
            unsigned int sx = (unsigned int)r[j];
            __builtin_assume(sx < (1u << 24));
            h[j] = *(const unsigned int*)((const char*)hv32 + ((sx << 8) | lb));
        }
#pragma unroll
        for (int j = 0; j < 16; ++j) {
            float w = __uint_as_float((unsigned int)(r[j] >> 32));
            z += w;
            floatx2 hf = { __uint_as_float(h[j] << 16),
                           __uint_as_float(h[j] & 0xFFFF0000u) };
            acc += hf * w;
        }
    }
    for (; i + 4 <= deg; i += 4) {
        unsigned long long r[4];
        unsigned int h[4];
#pragma unroll
        for (int j = 0; j < 4; ++j) r[j] = ep[i + j];
#pragma unroll
        for (int j = 0; j < 4; ++j) {
            unsigned int sx = (unsigned int)r[j];
            __builtin_assume(sx < (1u << 24));
            h[j] = *(const unsigned int*)((const char*)hv32 + ((sx << 8) | lb));
        }
#pragma unroll
        for (int j = 0; j < 4; ++j) {
            float w = __uint_as_float((unsigned int)(r[j] >> 32));
            z += w;
            floatx2 hf = { __uint_as_float(h[j] << 16),
                           __uint_as_float(h[j] & 0xFFFF0000u) };
            acc += hf * w;
        }
    }
    for (; i < deg; ++i) {
        unsigned long long r = ep[i];
        unsigned int sx = (unsigned int)r;
        __builtin_assume(sx < (1u << 24));
        unsigned int h = *(const unsigned int*)((const char*)hv32 + ((sx << 8) | lb));
        float w = __uint_as_float((unsigned int)(r >> 32));
        z += w;
        floatx2 hf = { __uint_as_float(h << 16),
                       __uint_as_float(h & 0xFFFF0000u) };
        acc += hf * w;
    }
    float rz = (z > 0.f) ? 1.f / z : 0.f;
    float x = acc.x * rz, y = acc.y * rz;
    x = x > 0.f ? x : expm1f(x);
    y = y > 0.f ? y : expm1f(y);
    ctx32[(size_t)n * 64 + lane] = ((unsigned int)f2b(y) << 16) | f2b(x);
}

// ---------------------------------------------------------------------------
// Fused MLP: out = relu(relu([ctx|nf] @ W1 + b1) @ W2 + b2).
// ---------------------------------------------------------------------------
__global__ __launch_bounds__(256) void mlp_fused(const unsigned short* __restrict__ ctx,
                                                 const void* __restrict__ nf,
                                                 const unsigned short* __restrict__ Wt1,
                                                 const void* __restrict__ b1,
                                                 const unsigned short* __restrict__ Wt2,
                                                 const void* __restrict__ b2,
                                                 void* __restrict__ outp,
                                                 const int* __restrict__ flag, int N) {
    __shared__ unsigned short Wl[128 * 72];
    __shared__ unsigned short Hl[4][32 * 136];
    const bool isbf = (*flag != 0);
    const int t = threadIdx.x, wid = t >> 6, lane = t & 63;
    const int m16 = lane & 15, quad = lane >> 4;
    const int row0 = blockIdx.x * 128;

    floatx4 acc[2][8];
#pragma unroll
    for (int i = 0; i < 2; ++i)
#pragma unroll
        for (int j = 0; j < 8; ++j) acc[i][j] = (floatx4){0.f, 0.f, 0.f, 0.f};

    int ra0 = row0 + wid * 32 + m16;      if (ra0 >= N) ra0 = N - 1;
    int ra1 = row0 + wid * 32 + 16 + m16; if (ra1 >= N) ra1 = N - 1;

    // ---- MLP1: acc = [ctx | nf] @ W1 ----
#pragma unroll
    for (int kc = 0; kc < 4; ++kc) {
        {
            int r = t >> 1, kh = (t & 1) * 32;
            const uint4* s = (const uint4*)(Wt1 + (size_t)r * 256 + kc * 64 + kh);
            uint4* d = (uint4*)&Wl[r * 72 + kh];
#pragma unroll
            for (int q = 0; q < 4; ++q) d[q] = s[q];
        }
        __syncthreads();
#pragma unroll
        for (int c = 0; c < 2; ++c) {
            int kl = c * 32 + quad * 8;
            int ka = kc * 64 + kl;
            bf16x8 a0, a1;
            if (ka < 128) {
                union { uint4 u; bf16x8 v; } t0, t1;
                t0.u = *(const uint4*)(ctx + (size_t)ra0 * 128 + ka);
                t1.u = *(const uint4*)(ctx + (size_t)ra1 * 128 + ka);
                a0 = t0.v; a1 = t1.v;
            } else {
                a0 = gfrag_dual(nf, ra0, 128, ka - 128, isbf);
                a1 = gfrag_dual(nf, ra1, 128, ka - 128, isbf);
            }
#pragma unroll
            for (int nt = 0; nt < 8; ++nt) {
                bf16x8 b = ldsfrag(&Wl[(nt * 16 + m16) * 72 + kl]);
                acc[0][nt] = __builtin_amdgcn_mfma_f32_16x16x32_bf16(a0, b, acc[0][nt], 0, 0, 0);
                acc[1][nt] = __builtin_amdgcn_mfma_f32_16x16x32_bf16(a1, b, acc[1][nt], 0, 0, 0);
            }
        }
        __syncthreads();
    }

    // ---- h = relu(acc + b1) -> per-wave LDS [row 0..31][col 0..127] ----
#pragma unroll
    for (int nt = 0; nt < 8; ++nt) {
        int col = nt * 16 + m16;
        float bb = load_dual(b1, col, isbf);
#pragma unroll
        for (int mt = 0; mt < 2; ++mt) {
#pragma unroll
            for (int rg = 0; rg < 4; ++rg) {
                int lr = mt * 16 + quad * 4 + rg;
                float x = acc[mt][nt][rg] + bb;
                Hl[wid][lr * 136 + col] = f2b(x > 0.f ? x : 0.f);
            }
        }
    }

#pragma unroll
    for (int i = 0; i < 2; ++i)
#pragma unroll
        for (int j = 0; j < 8; ++j) acc[i][j] = (floatx4){0.f, 0.f, 0.f, 0.f};

    // ---- MLP2: acc = h @ W2 ----
#pragma unroll
    for (int kc = 0; kc < 2; ++kc) {
        {
            int r = t >> 1, kh = (t & 1) * 32;
            const uint4* s = (const uint4*)(Wt2 + (size_t)r * 128 + kc * 64 + kh);
            uint4* d = (uint4*)&Wl[r * 72 + kh];
#pragma unroll
            for (int q = 0; q < 4; ++q) d[q] = s[q];
        }
        __syncthreads();
#pragma unroll
        for (int c = 0; c < 2; ++c) {
            int kl = c * 32 + quad * 8;
            int ka = kc * 64 + kl;
            bf16x8 a0 = ldsfrag(&Hl[wid][m16 * 136 + ka]);
            bf16x8 a1 = ldsfrag(&Hl[wid][(16 + m16) * 136 + ka]);
#pragma unroll
            for (int nt = 0; nt < 8; ++nt) {
                bf16x8 b = ldsfrag(&Wl[(nt * 16 + m16) * 72 + kl]);
                acc[0][nt] = __builtin_amdgcn_mfma_f32_16x16x32_bf16(a0, b, acc[0][nt], 0, 0, 0);
                acc[1][nt] = __builtin_amdgcn_mfma_f32_16x16x32_bf16(a1, b, acc[1][nt], 0, 0, 0);
            }
        }
        __syncthreads();
    }

    // ---- epilogue: out = relu(acc + b2), dual dtype ----
#pragma unroll
    for (int mt = 0; mt < 2; ++mt) {
        int gr0 = row0 + wid * 32 + mt * 16 + quad * 4;
#pragma unroll
        for (int nt = 0; nt < 8; ++nt) {
            int col = nt * 16 + m16;
            float bb = load_dual(b2, col, isbf);
#pragma unroll
            for (int rg = 0; rg < 4; ++rg) {
                int gr = gr0 + rg;
                if (gr < N) {
                    float x = acc[mt][nt][rg] + bb;
                    x = x > 0.f ? x : 0.f;
                    if (!isbf) ((float*)outp)[(size_t)gr * 128 + col] = x;
                    else       ((unsigned short*)outp)[(size_t)gr * 128 + col] = f2b(x);
                }
            }
        }
    }
}

// ---------------------------------------------------------------------------
extern "C" void kernel_launch(void* const* d_in, const int* in_sizes, int n_in,
                              void* d_out, int out_size, void* d_ws, size_t ws_size,
                              hipStream_t stream) {
    const void* node_feats  = d_in[0];
    const void* edge_logits = d_in[1];
    const void* W_proj      = d_in[2];
    const void* b_proj      = d_in[3];
    const void* W1          = d_in[4];
    const void* b1          = d_in[5];
    const void* W2          = d_in[6];
    const void* b2          = d_in[7];
    const int*  src         = (const int*)d_in[8];
    const int*  dst         = (const int*)d_in[9];

    const int N = in_sizes[0] / 128;
    const int E = in_sizes[8];
    const int NC = (N + CHUNK - 1) / CHUNK;   // scan chunks (<= 1024)

    char* ws = (char*)d_ws;
    size_t off = 0;
    unsigned short* hv  = (unsigned short*)(ws + off); off += (size_t)N * 256;
    unsigned short* ctx = (unsigned short*)(ws + off); off += (size_t)N * 256;
    uint2* rec = (uint2*)(ws + off); off += (size_t)E * 8;
    unsigned short* Wtp = (unsigned short*)(ws + off); off += 128 * 128 * 2;
    unsigned short* Wt1 = (unsigned short*)(ws + off); off += 128 * 256 * 2;
    unsigned short* Wt2 = (unsigned short*)(ws + off); off += 128 * 128 * 2;
    int* ncount    = (int*)(ws + off); off += (size_t)N * 4;
    int* row_start = (int*)(ws + off); off += (size_t)N * 4;
    int* cursor    = (int*)(ws + off); off += (size_t)N * 4;
    int* csum      = (int*)(ws + off); off += CHUNK * 4;
    int* cbase     = (int*)(ws + off); off += CHUNK * 4;
    int* flag      = (int*)(ws + off);

    const int gblocks = (N + 127) / 128;
    const int ablocks = (E + 1023) / 1024;    // 4 edges/thread

    // 1: dtype flag
    detect_kernel<<<1, 64, 0, stream>>>((const unsigned int*)node_feats, flag);
    // 2: zero degree counters
    hipMemsetAsync(ncount, 0, (size_t)N * 4, stream);
    // 3: degree count || weight transposes
    count_kernel<<<256 + CNT_BLOCKS, 256, 0, stream>>>(dst, ncount, E, W_proj, W1, W2,
                                                       Wtp, Wt1, Wt2, flag);
    // 4-6: three-tier exclusive scan -> row_start, cursor
    scanp_kernel<<<NC, 256, 0, stream>>>(ncount, row_start, csum, N);
    scant_kernel<<<1, 256, 0, stream>>>(csum, cbase, NC);
    addback_kernel<<<NC, 256, 0, stream>>>(row_start, cursor, cbase, N);
    // 7: projection GEMM || edge append (independent roles)
    gemm_append_kernel<<<gblocks + ablocks, 256, 0, stream>>>(node_feats, Wtp, b_proj,
                                                              hv, flag, N, gblocks,
                                                              dst, src, edge_logits,
                                                              cursor, rec, E);
    // 8: weighted aggregation + elu
    agg_csr_kernel<<<(N + 3) / 4, 256, 0, stream>>>(row_start, ncount,
                                                    (const unsigned long long*)rec,
                                                    (const unsigned int*)hv,
                                                    (unsigned int*)ctx, N);
    // 9: fused MLP
    mlp_fused<<<gblocks, 256, 0, stream>>>(ctx, node_feats, Wt1, b1, Wt2, b2,
                                           d_out, flag, N);
}

// Round 12
// 336.136 us; speedup vs baseline: 1.2684x; 1.2684x over previous
//
#include <hip/hip_runtime.h>
#include <hip/hip_bf16.h>

typedef __hip_bfloat16 bf16;
typedef __attribute__((ext_vector_type(8))) __bf16 bf16x8;
typedef __attribute__((ext_vector_type(4))) float floatx4;
typedef __attribute__((ext_vector_type(2))) float floatx2;

#define BUCKET_SHIFT 7
#define BUCKET_NODES 128
#define MAX_NB 1024
#define EPB 2048

__device__ __forceinline__ unsigned short f2b(float f) {
    bf16 h = __float2bfloat16(f);
    unsigned short s;
    __builtin_memcpy(&s, &h, 2);
    return s;
}
__device__ __forceinline__ float b2f(unsigned short u) {
    unsigned int x = ((unsigned int)u) << 16;
    float f;
    __builtin_memcpy(&f, &x, 4);
    return f;
}
__device__ __forceinline__ float load_dual(const void* p, long long i, bool isbf) {
    return isbf ? b2f(((const unsigned short*)p)[i]) : ((const float*)p)[i];
}
__device__ __forceinline__ bf16x8 ldsfrag(const unsigned short* p) {
    union { uint4 u; bf16x8 v; } t;
    t.u = *(const uint4*)p;
    return t.v;
}
// 8 bf16 A-fragment from a dual-dtype [rows][stride] matrix, row-major
__device__ __forceinline__ bf16x8 gfrag_dual(const void* A, int row, int stride, int k0, bool isbf) {
    if (isbf) {
        union { uint4 u; bf16x8 v; } t;
        t.u = *(const uint4*)((const unsigned short*)A + (size_t)row * stride + k0);
        return t.v;
    }
    const float* ap = (const float*)A + (size_t)row * stride + k0;
    float4 v0 = ((const float4*)ap)[0];
    float4 v1 = ((const float4*)ap)[1];
    union { unsigned short s[8]; bf16x8 v; } t;
    t.s[0] = f2b(v0.x); t.s[1] = f2b(v0.y); t.s[2] = f2b(v0.z); t.s[3] = f2b(v0.w);
    t.s[4] = f2b(v1.x); t.s[5] = f2b(v1.y); t.s[6] = f2b(v1.z); t.s[7] = f2b(v1.w);
    return t.v;
}

// ---------------------------------------------------------------------------
// Dtype detection + bcount zeroing.
// ---------------------------------------------------------------------------
__global__ __launch_bounds__(64) void detect_kernel(const unsigned int* __restrict__ words,
                                                    int* __restrict__ flag,
                                                    int* __restrict__ bcount) {
    for (int i = threadIdx.x; i < MAX_NB; i += 64) bcount[i] = 0;
    int cnt = 0;
    for (int i = threadIdx.x; i < 4096; i += 64) {
        unsigned int lo = words[i] & 0xFFFFu;
        unsigned int e = (lo >> 7) & 0xFFu;
        if (lo == 0u || (e >= 110u && e <= 135u)) cnt++;
    }
#pragma unroll
    for (int off = 32; off > 0; off >>= 1) cnt += __shfl_down(cnt, off, 64);
    if (threadIdx.x == 0) *flag = (cnt > 2458) ? 1 : 0;
}

// ---------------------------------------------------------------------------
// Fused: weight transposes (blocks [0,256)) + bucket histogram (rest).
// ---------------------------------------------------------------------------
__global__ __launch_bounds__(256) void prep_kernel(const void* __restrict__ Wp,
                                                   const void* __restrict__ W1,
                                                   const void* __restrict__ W2,
                                                   unsigned short* __restrict__ Wtp,
                                                   unsigned short* __restrict__ Wt1,
                                                   unsigned short* __restrict__ Wt2,
                                                   const int* __restrict__ flag,
                                                   const int* __restrict__ dst,
                                                   int* __restrict__ bcount, int E) {
    if (blockIdx.x < 256) {
        bool isbf = (*flag != 0);
        int idx = blockIdx.x * 256 + threadIdx.x;
        if (idx < 16384) {
            int n = idx >> 7, k = idx & 127;
            Wtp[idx] = f2b(load_dual(Wp, (long long)k * 128 + n, isbf));
        } else if (idx < 49152) {
            int j = idx - 16384;
            int n = j >> 8, k = j & 255;
            Wt1[j] = f2b(load_dual(W1, (long long)k * 128 + n, isbf));
        } else if (idx < 65536) {
            int j = idx - 49152;
            int n = j >> 7, k = j & 127;
            Wt2[j] = f2b(load_dual(W2, (long long)k * 128 + n, isbf));
        }
    } else {
        __shared__ int lcnt[MAX_NB];
        for (int i = threadIdx.x; i < MAX_NB; i += 256) lcnt[i] = 0;
        __syncthreads();
        int base = (blockIdx.x - 256) * EPB;
#pragma unroll
        for (int j = 0; j < EPB / 256; ++j) {
            int e = base + j * 256 + threadIdx.x;
            if (e < E) atomicAdd(&lcnt[dst[e] >> BUCKET_SHIFT], 1);
        }
        __syncthreads();
        for (int i = threadIdx.x; i < MAX_NB; i += 256)
            if (lcnt[i]) atomicAdd(&bcount[i], lcnt[i]);
    }
}

// ---------------------------------------------------------------------------
// Single-block exclusive scan of bucket counts (NB <= 1024) -> bstart, bcursor
// ---------------------------------------------------------------------------
__global__ __launch_bounds__(256) void bscan_kernel(const int* __restrict__ bcount,
                                                    int* __restrict__ bstart,
                                                    int* __restrict__ bcursor, int NB) {
    int t = threadIdx.x;
    int v[4];
    int sum = 0;
#pragma unroll
    for (int j = 0; j < 4; ++j) {
        int i = t * 4 + j;
        v[j] = (i < NB) ? bcount[i] : 0;
        sum += v[j];
    }
    int lane = t & 63, wave = t >> 6;
    int inc = sum;
#pragma unroll
    for (int off = 1; off < 64; off <<= 1) {
        int x = __shfl_up(inc, off, 64);
        if (lane >= off) inc += x;
    }
    __shared__ int wsum[4];
    if (lane == 63) wsum[wave] = inc;
    __syncthreads();
    int woff = 0;
    for (int w = 0; w < wave; ++w) woff += wsum[w];
    int run = inc - sum + woff;
#pragma unroll
    for (int j = 0; j < 4; ++j) {
        int i = t * 4 + j;
        if (i < NB) { bstart[i] = run; bcursor[i] = run; }
        run += v[j];
    }
}

// ---------------------------------------------------------------------------
// Fused: projection GEMM (blocks [0,gblocks)) + bucket append (rest).
// R11 edit: bappend (all pipes idle, pure latency) now hosts the MFMA-bound
// gemm instead of bcsr. R3 counters: bappend VALUBusy 2%, MfmaUtil 0, HBM 13%
// -> gemm rides in the idle pipes (m114: MFMA/memory waves co-schedule).
// ---------------------------------------------------------------------------
__global__ __launch_bounds__(256) void gemm_bappend_kernel(const void* __restrict__ A,
                                                           const unsigned short* __restrict__ Wt,
                                                           const void* __restrict__ bias,
                                                           unsigned short* __restrict__ hv,
                                                           const int* __restrict__ flag, int N,
                                                           int gblocks,
                                                           const int* __restrict__ dst,
                                                           const int* __restrict__ src,
                                                           const void* __restrict__ logits,
                                                           int* __restrict__ bcursor,
                                                           uint2* __restrict__ ebuf, int E) {
    __shared__ unsigned short Wl[128 * 136];   // 34.8KB, overlaid by append role
    const int t = threadIdx.x;
    if ((int)blockIdx.x < gblocks) {
        // ---- projection GEMM role ----
        const bool isbf = (*flag != 0);
        const int wid = t >> 6, lane = t & 63;
        const int m16 = lane & 15, quad = lane >> 4;
        const int row0 = blockIdx.x * 128;
        {
            int r = t >> 1, kh = (t & 1) * 64;
            const uint4* s = (const uint4*)(Wt + (size_t)r * 128 + kh);
            uint4* d = (uint4*)&Wl[r * 136 + kh];
#pragma unroll
            for (int q = 0; q < 8; ++q) d[q] = s[q];
        }
        __syncthreads();

        floatx4 acc[2][8];
#pragma unroll
        for (int i = 0; i < 2; ++i)
#pragma unroll
            for (int j = 0; j < 8; ++j) acc[i][j] = (floatx4){0.f, 0.f, 0.f, 0.f};

        int ra0 = row0 + wid * 32 + m16;      if (ra0 >= N) ra0 = N - 1;
        int ra1 = row0 + wid * 32 + 16 + m16; if (ra1 >= N) ra1 = N - 1;

#pragma unroll
        for (int c = 0; c < 4; ++c) {
            int k0 = c * 32 + quad * 8;
            bf16x8 a0 = gfrag_dual(A, ra0, 128, k0, isbf);
            bf16x8 a1 = gfrag_dual(A, ra1, 128, k0, isbf);
#pragma unroll
            for (int nt = 0; nt < 8; ++nt) {
                bf16x8 b = ldsfrag(&Wl[(nt * 16 + m16) * 136 + k0]);
                acc[0][nt] = __builtin_amdgcn_mfma_f32_16x16x32_bf16(a0, b, acc[0][nt], 0, 0, 0);
                acc[1][nt] = __builtin_amdgcn_mfma_f32_16x16x32_bf16(a1, b, acc[1][nt], 0, 0, 0);
            }
        }

#pragma unroll
        for (int mt = 0; mt < 2; ++mt) {
            int gr0 = row0 + wid * 32 + mt * 16 + quad * 4;
#pragma unroll
            for (int nt = 0; nt < 8; ++nt) {
                int col = nt * 16 + m16;
                float bb = load_dual(bias, col, isbf);
#pragma unroll
                for (int rg = 0; rg < 4; ++rg) {
                    int gr = gr0 + rg;
                    if (gr < N) hv[(size_t)gr * 128 + col] = f2b(acc[mt][nt][rg] + bb);
                }
            }
        }
    } else {
        // ---- bucket append role (LDS overlaid on Wl) ----
        int* lcnt = (int*)Wl;
        int* lbase = lcnt + MAX_NB;
        for (int i = t; i < MAX_NB; i += 256) lcnt[i] = 0;
        __syncthreads();
        const bool isbf = (*flag != 0);
        int base = ((int)blockIdx.x - gblocks) * EPB;
#pragma unroll
        for (int j = 0; j < EPB / 256; ++j) {
            int e = base + j * 256 + t;
            if (e < E) atomicAdd(&lcnt[dst[e] >> BUCKET_SHIFT], 1);
        }
        __syncthreads();
        for (int i = t; i < MAX_NB; i += 256) {
            int c = lcnt[i];
            if (c) { lbase[i] = atomicAdd(&bcursor[i], c); lcnt[i] = 0; }
        }
        __syncthreads();
#pragma unroll
        for (int j = 0; j < EPB / 256; ++j) {
            int e = base + j * 256 + t;
            if (e < E) {
                int d = dst[e];
                int b = d >> BUCKET_SHIFT;
                float w = expf(load_dual(logits, e, isbf));
                int pos = lbase[b] + atomicAdd(&lcnt[b], 1);
                uint2 rec;
                rec.x = (unsigned int)src[e] | ((unsigned int)(d & (BUCKET_NODES - 1)) << 24);
                rec.y = __float_as_uint(w);
                ebuf[pos] = rec;
            }
        }
    }
}

// ---------------------------------------------------------------------------
// Bucket-local CSR (standalone): one block per bucket; count/scan/scatter
// node-sorted records into a contiguous window. Contiguous read + write.
// ---------------------------------------------------------------------------
__global__ __launch_bounds__(256) void bcsr_kernel(const uint2* __restrict__ ebuf,
                                                   const int* __restrict__ bstart,
                                                   const int* __restrict__ bcount,
                                                   uint2* __restrict__ ebuf2,
                                                   int* __restrict__ row_start,
                                                   int* __restrict__ ncount, int N) {
    __shared__ int lcnt[BUCKET_NODES];
    __shared__ int lbase[BUCKET_NODES];
    const int b = blockIdx.x;
    const int s0 = bstart[b];
    const int cnt = bcount[b];
    if (threadIdx.x < BUCKET_NODES) lcnt[threadIdx.x] = 0;
    __syncthreads();
    for (int i = threadIdx.x; i < cnt; i += 256)
        atomicAdd(&lcnt[ebuf[s0 + i].x >> 24], 1);
    __syncthreads();
    if (threadIdx.x < 64) {
        int lane = threadIdx.x;
        int carry = 0;
#pragma unroll
        for (int half = 0; half < 2; ++half) {
            int idx = half * 64 + lane;
            int v = lcnt[idx];
            int inc = v;
#pragma unroll
            for (int off = 1; off < 64; off <<= 1) {
                int x = __shfl_up(inc, off, 64);
                if (lane >= off) inc += x;
            }
            lbase[idx] = carry + inc - v;
            carry += __shfl(inc, 63, 64);
        }
    }
    __syncthreads();
    if (threadIdx.x < BUCKET_NODES) {
        int gn = b * BUCKET_NODES + threadIdx.x;
        if (gn < N) {
            row_start[gn] = s0 + lbase[threadIdx.x];
            ncount[gn] = lcnt[threadIdx.x];
        }
    }
    __syncthreads();
    if (threadIdx.x < BUCKET_NODES) lcnt[threadIdx.x] = 0;
    __syncthreads();
    for (int i = threadIdx.x; i < cnt; i += 256) {
        uint2 rec = ebuf[s0 + i];
        int dl = rec.x >> 24;
        int pos = lbase[dl] + atomicAdd(&lcnt[dl], 1);
        ebuf2[s0 + pos] = make_uint2(rec.x & 0xFFFFFFu, rec.y);
    }
}

// ---------------------------------------------------------------------------
// Aggregation: one wave/node, 2 features/lane, register accumulation.
// Wave-uniform record stream via readfirstlane, 16-deep gather pipeline,
// 32-bit offset gather addressing, packed float2 accumulate.
// ---------------------------------------------------------------------------
__global__ __launch_bounds__(256) void agg_csr_kernel(const int* __restrict__ row_start,
                                                      const int* __restrict__ ncount,
                                                      const unsigned long long* __restrict__ erec,
                                                      const unsigned int* __restrict__ hv32,
                                                      unsigned int* __restrict__ ctx32, int N) {
    int n = blockIdx.x * 4 + (threadIdx.x >> 6);
    int lane = threadIdx.x & 63;
    if (n >= N) return;
    int s0 = __builtin_amdgcn_readfirstlane(row_start[n]);
    int deg = __builtin_amdgcn_readfirstlane(ncount[n]);
    const unsigned long long* ep = erec + s0;
    const unsigned int lb = (unsigned int)lane << 2;
    floatx2 acc = {0.f, 0.f};
    float z = 0.f;
    int i = 0;
    for (; i + 16 <= deg; i += 16) {
        unsigned long long r[16];
        unsigned int h[16];
#pragma unroll
        for (int j = 0; j < 16; ++j) r[j] = ep[i + j];
#pragma unroll
        for (int j = 0; j < 16; ++j) {
            unsigned int sx = (unsigned int)r[j];
            __builtin_assume(sx < (1u << 24));
            h[j] = *(const unsigned int*)((const char*)hv32 + ((sx << 8) | lb));
        }
#pragma unroll
        for (int j = 0; j < 16; ++j) {
            float w = __uint_as_float((unsigned int)(r[j] >> 32));
            z += w;
            floatx2 hf = { __uint_as_float(h[j] << 16),
                           __uint_as_float(h[j] & 0xFFFF0000u) };
            acc += hf * w;
        }
    }
    for (; i + 4 <= deg; i += 4) {
        unsigned long long r[4];
        unsigned int h[4];
#pragma unroll
        for (int j = 0; j < 4; ++j) r[j] = ep[i + j];
#pragma unroll
        for (int j = 0; j < 4; ++j) {
            unsigned int sx = (unsigned int)r[j];
            __builtin_assume(sx < (1u << 24));
            h[j] = *(const unsigned int*)((const char*)hv32 + ((sx << 8) | lb));
        }
#pragma unroll
        for (int j = 0; j < 4; ++j) {
            float w = __uint_as_float((unsigned int)(r[j] >> 32));
            z += w;
            floatx2 hf = { __uint_as_float(h[j] << 16),
                           __uint_as_float(h[j] & 0xFFFF0000u) };
            acc += hf * w;
        }
    }
    for (; i < deg; ++i) {
        unsigned long long r = ep[i];
        unsigned int sx = (unsigned int)r;
        __builtin_assume(sx < (1u << 24));
        unsigned int h = *(const unsigned int*)((const char*)hv32 + ((sx << 8) | lb));
        float w = __uint_as_float((unsigned int)(r >> 32));
        z += w;
        floatx2 hf = { __uint_as_float(h << 16),
                       __uint_as_float(h & 0xFFFF0000u) };
        acc += hf * w;
    }
    float rz = (z > 0.f) ? 1.f / z : 0.f;
    float x = acc.x * rz, y = acc.y * rz;
    x = x > 0.f ? x : expm1f(x);
    y = y > 0.f ? y : expm1f(y);
    ctx32[(size_t)n * 64 + lane] = ((unsigned int)f2b(y) << 16) | f2b(x);
}

// ---------------------------------------------------------------------------
// Fused MLP: out = relu(relu([ctx|nf] @ W1 + b1) @ W2 + b2).
// ---------------------------------------------------------------------------
__global__ __launch_bounds__(256) void mlp_fused(const unsigned short* __restrict__ ctx,
                                                 const void* __restrict__ nf,
                                                 const unsigned short* __restrict__ Wt1,
                                                 const void* __restrict__ b1,
                                                 const unsigned short* __restrict__ Wt2,
                                                 const void* __restrict__ b2,
                                                 void* __restrict__ outp,
                                                 const int* __restrict__ flag, int N) {
    __shared__ unsigned short Wl[128 * 72];
    __shared__ unsigned short Hl[4][32 * 136];
    const bool isbf = (*flag != 0);
    const int t = threadIdx.x, wid = t >> 6, lane = t & 63;
    const int m16 = lane & 15, quad = lane >> 4;
    const int row0 = blockIdx.x * 128;

    floatx4 acc[2][8];
#pragma unroll
    for (int i = 0; i < 2; ++i)
#pragma unroll
        for (int j = 0; j < 8; ++j) acc[i][j] = (floatx4){0.f, 0.f, 0.f, 0.f};

    int ra0 = row0 + wid * 32 + m16;      if (ra0 >= N) ra0 = N - 1;
    int ra1 = row0 + wid * 32 + 16 + m16; if (ra1 >= N) ra1 = N - 1;

    // ---- MLP1: acc = [ctx | nf] @ W1 ----
#pragma unroll
    for (int kc = 0; kc < 4; ++kc) {
        {
            int r = t >> 1, kh = (t & 1) * 32;
            const uint4* s = (const uint4*)(Wt1 + (size_t)r * 256 + kc * 64 + kh);
            uint4* d = (uint4*)&Wl[r * 72 + kh];
#pragma unroll
            for (int q = 0; q < 4; ++q) d[q] = s[q];
        }
        __syncthreads();
#pragma unroll
        for (int c = 0; c < 2; ++c) {
            int kl = c * 32 + quad * 8;
            int ka = kc * 64 + kl;
            bf16x8 a0, a1;
            if (ka < 128) {
                union { uint4 u; bf16x8 v; } t0, t1;
                t0.u = *(const uint4*)(ctx + (size_t)ra0 * 128 + ka);
                t1.u = *(const uint4*)(ctx + (size_t)ra1 * 128 + ka);
                a0 = t0.v; a1 = t1.v;
            } else {
                a0 = gfrag_dual(nf, ra0, 128, ka - 128, isbf);
                a1 = gfrag_dual(nf, ra1, 128, ka - 128, isbf);
            }
#pragma unroll
            for (int nt = 0; nt < 8; ++nt) {
                bf16x8 b = ldsfrag(&Wl[(nt * 16 + m16) * 72 + kl]);
                acc[0][nt] = __builtin_amdgcn_mfma_f32_16x16x32_bf16(a0, b, acc[0][nt], 0, 0, 0);
                acc[1][nt] = __builtin_amdgcn_mfma_f32_16x16x32_bf16(a1, b, acc[1][nt], 0, 0, 0);
            }
        }
        __syncthreads();
    }

    // ---- h = relu(acc + b1) -> per-wave LDS [row 0..31][col 0..127] ----
#pragma unroll
    for (int nt = 0; nt < 8; ++nt) {
        int col = nt * 16 + m16;
        float bb = load_dual(b1, col, isbf);
#pragma unroll
        for (int mt = 0; mt < 2; ++mt) {
#pragma unroll
            for (int rg = 0; rg < 4; ++rg) {
                int lr = mt * 16 + quad * 4 + rg;
                float x = acc[mt][nt][rg] + bb;
                Hl[wid][lr * 136 + col] = f2b(x > 0.f ? x : 0.f);
            }
        }
    }

#pragma unroll
    for (int i = 0; i < 2; ++i)
#pragma unroll
        for (int j = 0; j < 8; ++j) acc[i][j] = (floatx4){0.f, 0.f, 0.f, 0.f};

    // ---- MLP2: acc = h @ W2 ----
#pragma unroll
    for (int kc = 0; kc < 2; ++kc) {
        {
            int r = t >> 1, kh = (t & 1) * 32;
            const uint4* s = (const uint4*)(Wt2 + (size_t)r * 128 + kc * 64 + kh);
            uint4* d = (uint4*)&Wl[r * 72 + kh];
#pragma unroll
            for (int q = 0; q < 4; ++q) d[q] = s[q];
        }
        __syncthreads();
#pragma unroll
        for (int c = 0; c < 2; ++c) {
            int kl = c * 32 + quad * 8;
            int ka = kc * 64 + kl;
            bf16x8 a0 = ldsfrag(&Hl[wid][m16 * 136 + ka]);
            bf16x8 a1 = ldsfrag(&Hl[wid][(16 + m16) * 136 + ka]);
#pragma unroll
            for (int nt = 0; nt < 8; ++nt) {
                bf16x8 b = ldsfrag(&Wl[(nt * 16 + m16) * 72 + kl]);
                acc[0][nt] = __builtin_amdgcn_mfma_f32_16x16x32_bf16(a0, b, acc[0][nt], 0, 0, 0);
                acc[1][nt] = __builtin_amdgcn_mfma_f32_16x16x32_bf16(a1, b, acc[1][nt], 0, 0, 0);
            }
        }
        __syncthreads();
    }

    // ---- epilogue: out = relu(acc + b2), dual dtype ----
#pragma unroll
    for (int mt = 0; mt < 2; ++mt) {
        int gr0 = row0 + wid * 32 + mt * 16 + quad * 4;
#pragma unroll
        for (int nt = 0; nt < 8; ++nt) {
            int col = nt * 16 + m16;
            float bb = load_dual(b2, col, isbf);
#pragma unroll
            for (int rg = 0; rg < 4; ++rg) {
                int gr = gr0 + rg;
                if (gr < N) {
                    float x = acc[mt][nt][rg] + bb;
                    x = x > 0.f ? x : 0.f;
                    if (!isbf) ((float*)outp)[(size_t)gr * 128 + col] = x;
                    else       ((unsigned short*)outp)[(size_t)gr * 128 + col] = f2b(x);
                }
            }
        }
    }
}

// ---------------------------------------------------------------------------
extern "C" void kernel_launch(void* const* d_in, const int* in_sizes, int n_in,
                              void* d_out, int out_size, void* d_ws, size_t ws_size,
                              hipStream_t stream) {
    const void* node_feats  = d_in[0];
    const void* edge_logits = d_in[1];
    const void* W_proj      = d_in[2];
    const void* b_proj      = d_in[3];
    const void* W1          = d_in[4];
    const void* b1          = d_in[5];
    const void* W2          = d_in[6];
    const void* b2          = d_in[7];
    const int*  src         = (const int*)d_in[8];
    const int*  dst         = (const int*)d_in[9];

    const int N = in_sizes[0] / 128;
    const int E = in_sizes[8];
    const int NB = (N + BUCKET_NODES - 1) / BUCKET_NODES;   // <= 1024

    char* ws = (char*)d_ws;
    size_t off = 0;
    unsigned short* hv  = (unsigned short*)(ws + off); off += (size_t)N * 256;
    unsigned short* ctx = (unsigned short*)(ws + off); off += (size_t)N * 256;
    uint2* ebuf  = (uint2*)(ws + off); off += (size_t)E * 8;
    uint2* ebuf2 = (uint2*)(ws + off); off += (size_t)E * 8;
    unsigned short* Wtp = (unsigned short*)(ws + off); off += 128 * 128 * 2;
    unsigned short* Wt1 = (unsigned short*)(ws + off); off += 128 * 256 * 2;
    unsigned short* Wt2 = (unsigned short*)(ws + off); off += 128 * 128 * 2;
    int* bcount    = (int*)(ws + off); off += MAX_NB * 4;
    int* bstart    = (int*)(ws + off); off += MAX_NB * 4;
    int* bcursor   = (int*)(ws + off); off += MAX_NB * 4;
    int* row_start = (int*)(ws + off); off += (size_t)N * 4;
    int* ncount    = (int*)(ws + off); off += (size_t)N * 4;
    int* flag      = (int*)(ws + off);

    const int gblocks = (N + 127) / 128;
    const int ebblocks = (E + EPB - 1) / EPB;

    // 1: dtype flag + bcount zero
    detect_kernel<<<1, 64, 0, stream>>>((const unsigned int*)node_feats, flag, bcount);
    // 2: weight transposes || bucket histogram
    prep_kernel<<<256 + ebblocks, 256, 0, stream>>>(W_proj, W1, W2, Wtp, Wt1, Wt2,
                                                    flag, dst, bcount, E);
    // 3: bucket scan
    bscan_kernel<<<1, 256, 0, stream>>>(bcount, bstart, bcursor, NB);
    // 4: projection GEMM || bucket append (gemm hides append's idle latency)
    gemm_bappend_kernel<<<gblocks + ebblocks, 256, 0, stream>>>(node_feats, Wtp, b_proj,
                                                                hv, flag, N, gblocks,
                                                                dst, src, edge_logits,
                                                                bcursor, ebuf, E);
    // 5: bucket-local CSR (standalone; contiguous read/write)
    bcsr_kernel<<<NB, 256, 0, stream>>>(ebuf, bstart, bcount, ebuf2,
                                        row_start, ncount, N);
    // 6: weighted aggregation + elu
    agg_csr_kernel<<<(N + 3) / 4, 256, 0, stream>>>(row_start, ncount,
                                                    (const unsigned long long*)ebuf2,
                                                    (const unsigned int*)hv,
                                                    (unsigned int*)ctx, N);
    // 7: fused MLP
    mlp_fused<<<gblocks, 256, 0, stream>>>(ctx, node_feats, Wt1, b1, Wt2, b2,
                                           d_out, flag, N);
}